// Round 11
// baseline (225.408 us; speedup 1.0000x reference)
//
#include <hip/hip_runtime.h>

// MLP depends only on X[b] (1000 distinct values). R11: h2 eliminated —
// mlp2's epilogue reduces relu(acc+b) against Wout in-register (shfl
// butterfly over the 16 n-lanes) and atomicAdds 1000x5 f32 logits into
// tableRaw (zeroed by prep); scan applies sigmoid+clip(logit+bout) per
// chain thread. 4 dispatches: prep -> mlp1 -> mlp2 -> scan.
// Kept lessons: R5 strided stores = 4.85x write amp (LDS-staged contiguous
// stores); R7 grid.sync ~60us/barrier (no coop); R8 per-load dtype branches
// at 1 block/CU = latency death (fb hoisted, MFMA tiling for W reuse);
// params dedup via per-xi table is 67x cheaper than per-row recompute.

typedef unsigned int uint;
typedef unsigned char uchar;
typedef unsigned short ushort_t;
typedef __attribute__((ext_vector_type(8))) short short8;
typedef __attribute__((ext_vector_type(4))) float f32x4;
typedef __attribute__((ext_vector_type(2))) uint uint2v;

#define SS 1000
#define HH 512
#define TT 200
#define BB_ 65536
#define PP 5

#define OFF_EMB   0
#define OFF_B1    512000
#define OFF_B2    512512
#define CONV_TOT  513024      // embed + b1 + b2 (all multiples of 4)

__device__ __forceinline__ float b2f(ushort_t u) {
    return __uint_as_float(((uint)u) << 16);
}
__device__ __forceinline__ ushort_t f2b(float f) {
    uint u = __float_as_uint(f);
    uint r = u + 0x7FFFu + ((u >> 16) & 1u);   // RNE
    return (ushort_t)(r >> 16);
}
// Per-wave dtype detect (R2-R10: dataset is f32; keep both paths).
__device__ __forceinline__ int detect_bf16(const uint* __restrict__ embed_raw,
                                           int tid) {
    uint w = embed_raw[tid & 63];
    uint e = (w >> 7) & 0xFFu;
    bool pl = (e >= 117u && e <= 130u);
    return __popcll(__ballot(pl)) >= 32 ? 1 : 0;
}
__device__ __forceinline__ ushort_t ld_bf16(const void* src, int idx, int fb) {
    return fb ? ((const ushort_t*)src)[idx] : f2b(((const float*)src)[idx]);
}
__device__ __forceinline__ float ldf(const void* src, int idx, int fb) {
    return fb ? b2f(((const ushort_t*)src)[idx]) : ((const float*)src)[idx];
}

// The one true scan step (same fp ops/order everywhere).
__device__ __forceinline__ float bkt_step(float latent, bool yt,
                                          float oms, float omg, float A1,
                                          float A0, float g, float s,
                                          float oml, float l) {
    float num1    = latent * oms;
    float correct = fmaf(latent, A1, g);
    float lats    = latent * s;
    float num = yt ? num1 : lats;
    float den = yt ? correct : fmaf(latent, A0, omg);
    float kt  = num * __builtin_amdgcn_rcpf(den);
    float nxt = fmaf(kt, oml, l);
    return fminf(fmaxf(nxt, 1e-6f), 1.f - 1e-6f);
}

// ------------------------------------------------------------------- prep
// [0,501): vectorized conv copy (embed+b1+b2 -> bf16). [501,1013): 32x32
// transpose tiles of W1/W2. [1013,1033): zero tableRaw (5000 f32).
__global__ __launch_bounds__(256) void prep_kernel(
    const void* __restrict__ embed, const void* __restrict__ W1,
    const void* __restrict__ b1,    const void* __restrict__ W2,
    const void* __restrict__ b2,
    ushort_t* __restrict__ conv, ushort_t* __restrict__ WT1,
    ushort_t* __restrict__ WT2,  float* __restrict__ tableRaw)
{
    int tid = threadIdx.x;
    int fb = detect_bf16((const uint*)embed, tid);
    int bx = blockIdx.x;
    if (bx < 501) {
        int i = (bx * 256 + tid) * 4;
        if (i < CONV_TOT) {
            const void* src; int off;
            if      (i < OFF_B1)   { src = embed; off = i; }
            else if (i < OFF_B2)   { src = b1;    off = i - OFF_B1; }
            else                   { src = b2;    off = i - OFF_B2; }
            ushort4 o;
            if (fb) {
                ushort4 v = *(const ushort4*)((const ushort_t*)src + off);
                o = v;
            } else {
                float4 v = *(const float4*)((const float*)src + off);
                o.x = f2b(v.x); o.y = f2b(v.y); o.z = f2b(v.z); o.w = f2b(v.w);
            }
            *(ushort4*)(conv + i) = o;
        }
    } else if (bx < 1013) {
        __shared__ ushort_t t[32][33];
        int bi = bx - 501;
        const void* W = bi < 256 ? W1 : W2;
        ushort_t* WT = bi < 256 ? WT1 : WT2;
        int ti = bi & 255;
        int k0 = (ti & 15) * 32, n0 = (ti >> 4) * 32;
        int tx = tid & 31, ty = tid >> 5;
        #pragma unroll
        for (int i = ty; i < 32; i += 8)
            t[i][tx] = ld_bf16(W, (k0 + i) * HH + n0 + tx, fb);
        __syncthreads();
        #pragma unroll
        for (int i = ty; i < 32; i += 8)
            WT[(n0 + i) * HH + k0 + tx] = t[tx][i];
    } else {
        int idx = (bx - 1013) * 256 + tid;
        if (idx < SS * PP) tableRaw[idx] = 0.f;
    }
}

// ------------------------------------------------------------ MLP layer 1
// Wave computes a 16x16 MFMA tile; grid (16,32)=512 blocks (2/CU).
__global__ __launch_bounds__(256) void mlp_layer(
    const ushort_t* __restrict__ A, const ushort_t* __restrict__ WT,
    const ushort_t* __restrict__ bias, ushort_t* __restrict__ H, int Mclamp)
{
    int tid = threadIdx.x;
    int lane = tid & 63;
    int wave = tid >> 6;
    int m_base = blockIdx.x * 64 + wave * 16;
    int n_base = blockIdx.y * 16;
    int lrow = lane & 15;
    int q = lane >> 4;
    int rowA = m_base + lrow; if (rowA > Mclamp) rowA = Mclamp;

    const short8* Ap = (const short8*)(A + (size_t)rowA * HH) + q;
    const short8* Bp = (const short8*)(WT + (size_t)(n_base + lrow) * HH) + q;

    f32x4 acc = {0.f, 0.f, 0.f, 0.f};
    #pragma unroll 8
    for (int kk = 0; kk < 16; kk++) {
        short8 a = Ap[kk * 4];
        short8 b = Bp[kk * 4];
        acc = __builtin_amdgcn_mfma_f32_16x16x32_bf16(a, b, acc, 0, 0, 0);
    }

    int orow = m_base + q * 4;                 // C/D: col=lane&15, row=q*4+reg
    int n = n_base + lrow;
    float bb = b2f(bias[n]);
    #pragma unroll
    for (int r = 0; r < 4; r++) {
        float v = acc[r] + bb;
        H[(size_t)(orow + r) * HH + n] = f2b(fmaxf(v, 0.f));
    }
}

// ------------------------------------------------- MLP layer 2 + logit dots
// Same tile compute; epilogue reduces relu(acc+b) vs Wout[n][0..4] across
// the 16 n-lanes (shfl butterfly over lane bits 0-3 = lrow) and atomicAdds
// 4 rows x 5 p partials into tableRaw. No h2 materialization.
__global__ __launch_bounds__(256) void mlp2_kernel(
    const ushort_t* __restrict__ A, const ushort_t* __restrict__ WT,
    const ushort_t* __restrict__ bias, const void* __restrict__ Wout,
    const uint* __restrict__ embed_raw, float* __restrict__ tableRaw)
{
    int tid = threadIdx.x;
    int fb = detect_bf16(embed_raw, tid);
    int lane = tid & 63;
    int wave = tid >> 6;
    int m_base = blockIdx.x * 64 + wave * 16;
    int n_base = blockIdx.y * 16;
    int lrow = lane & 15;
    int q = lane >> 4;
    int rowA = m_base + lrow; if (rowA > 1023) rowA = 1023;

    const short8* Ap = (const short8*)(A + (size_t)rowA * HH) + q;
    const short8* Bp = (const short8*)(WT + (size_t)(n_base + lrow) * HH) + q;

    f32x4 acc = {0.f, 0.f, 0.f, 0.f};
    #pragma unroll 8
    for (int kk = 0; kk < 16; kk++) {
        short8 a = Ap[kk * 4];
        short8 b = Bp[kk * 4];
        acc = __builtin_amdgcn_mfma_f32_16x16x32_bf16(a, b, acc, 0, 0, 0);
    }

    int orow = m_base + q * 4;
    int n = n_base + lrow;
    float bb = b2f(bias[n]);
    float h[4];
    #pragma unroll
    for (int r = 0; r < 4; r++)
        h[r] = fmaxf(acc[r] + bb, 0.f);

    float w[5];
    if (fb) {
        const ushort_t* W16 = (const ushort_t*)Wout;
        #pragma unroll
        for (int p = 0; p < 5; p++) w[p] = b2f(W16[n * 5 + p]);
    } else {
        const float* W32 = (const float*)Wout;
        #pragma unroll
        for (int p = 0; p < 5; p++) w[p] = W32[n * 5 + p];
    }

    float sdot[5][4];
    #pragma unroll
    for (int p = 0; p < 5; p++)
        #pragma unroll
        for (int r = 0; r < 4; r++)
            sdot[p][r] = h[r] * w[p];
    // butterfly over lrow (lane bits 0-3): sums the 16 n-contributions
    #pragma unroll
    for (int m = 1; m < 16; m <<= 1)
        #pragma unroll
        for (int p = 0; p < 5; p++)
            #pragma unroll
            for (int r = 0; r < 4; r++)
                sdot[p][r] += __shfl_xor(sdot[p][r], m);

    if (lrow == 0 && orow < SS) {              // 1000 % 4 == 0: clean cut
        #pragma unroll
        for (int r = 0; r < 4; r++)
            #pragma unroll
            for (int p = 0; p < 5; p++)
                atomicAdd(&tableRaw[(orow + r) * 5 + p], sdot[p][r]);
    }
}

// ---------------------------------------------------------------- scan
// One block = 32 rows. Phase 0: y -> LDS nibbles. Phase A: 32 exact
// 200-step chains (8 lanes x 4 waves) gather logits -> sigmoid+clip ->
// params out + latents into the 32x200 LDS tile. Sweep: corrects =
// fma(latent, A1, g); contiguous nontemporal stores.
__global__ __launch_bounds__(256) void scan_kernel(
    const int* __restrict__ X, const int* __restrict__ y,
    const float* __restrict__ tableRaw, const void* __restrict__ bout,
    const uint* __restrict__ embed_raw, void* __restrict__ out)
{
    __shared__ __align__(16) float stg[32 * 200];      // 25600 B
    __shared__ uchar ybit[32 * 50];                    // 1600 B
    __shared__ float pA1[32], pG[32];
    int tid = threadIdx.x;
    int rbase = blockIdx.x * 32;
    int fb = detect_bf16(embed_raw, tid);

    // phase 0
    for (int idx = tid; idx < 1600; idx += 256) {
        int r = idx / 50, k = idx - r * 50;
        int4 v = *(const int4*)(y + (size_t)(rbase + r) * TT + k * 4);
        ybit[r * 50 + k] = (uchar)((uint)(v.x == 1) | ((uint)(v.y == 1) << 1) |
                                   ((uint)(v.z == 1) << 2) | ((uint)(v.w == 1) << 3));
    }
    __syncthreads();

    // phase A
    int lane = tid & 63, wv = tid >> 6;
    if (lane < 8) {
        int r = wv * 8 + lane;                 // 0..31
        int rg = rbase + r;
        int xi = X[rg]; xi = xi < 0 ? 0 : (xi >= SS ? SS - 1 : xi);
        float lg[5];
        #pragma unroll
        for (int p = 0; p < 5; p++) {
            float logit = tableRaw[xi * 5 + p] + ldf(bout, p, fb);
            float sg = 1.f / (1.f + expf(-logit));
            lg[p] = fminf(fmaxf(sg, 1e-6f), 1.f - 1e-6f);
        }
        float l = lg[0], g = lg[2], s = lg[3], L0 = lg[4];
        float oms = 1.f - s, omg = 1.f - g, oml = 1.f - l;
        float A1 = 1.f - s - g, A0 = s + g - 1.f;
        pA1[r] = A1; pG[r] = g;

        if (fb) {
            ushort_t* pp = (ushort_t*)out + 2ull * BB_ * TT + (size_t)rg * 5;
            #pragma unroll
            for (int p = 0; p < 5; p++) pp[p] = f2b(lg[p]);
        } else {
            float* pp = (float*)out + 2ull * BB_ * TT + (size_t)rg * 5;
            #pragma unroll
            for (int p = 0; p < 5; p++) pp[p] = lg[p];
        }

        float latent = L0;
        const uchar* yb = &ybit[r * 50];
        float* srow = &stg[r * 200];
        for (int k = 0; k < 50; k++) {
            uint nib = yb[k];
            #pragma unroll
            for (int i = 0; i < 4; i++) {
                srow[k * 4 + i] = latent;
                latent = bkt_step(latent, (nib >> i) & 1u,
                                  oms, omg, A1, A0, g, s, oml, l);
            }
        }
    }
    __syncthreads();

    // sweep
    const f32x4* src = (const f32x4*)stg;
    if (!fb) {
        f32x4* dc = (f32x4*)((float*)out + (size_t)rbase * TT);
        f32x4* dl = (f32x4*)((float*)out + (size_t)BB_ * TT + (size_t)rbase * TT);
        for (int idx = tid; idx < 1600; idx += 256) {
            int r = idx / 50;
            f32x4 v = src[idx];
            float A1 = pA1[r], g = pG[r];
            f32x4 c;
            c[0] = fmaf(v[0], A1, g); c[1] = fmaf(v[1], A1, g);
            c[2] = fmaf(v[2], A1, g); c[3] = fmaf(v[3], A1, g);
            __builtin_nontemporal_store(v, dl + idx);
            __builtin_nontemporal_store(c, dc + idx);
        }
    } else {
        uint2v* dc = (uint2v*)((ushort_t*)out + (size_t)rbase * TT);
        uint2v* dl = (uint2v*)((ushort_t*)out + (size_t)BB_ * TT + (size_t)rbase * TT);
        for (int idx = tid; idx < 1600; idx += 256) {
            int r = idx / 50;
            f32x4 v = src[idx];
            float A1 = pA1[r], g = pG[r];
            uint2v lv, cv;
            lv[0] = (uint)f2b(v[0]) | ((uint)f2b(v[1]) << 16);
            lv[1] = (uint)f2b(v[2]) | ((uint)f2b(v[3]) << 16);
            cv[0] = (uint)f2b(fmaf(v[0], A1, g)) | ((uint)f2b(fmaf(v[1], A1, g)) << 16);
            cv[1] = (uint)f2b(fmaf(v[2], A1, g)) | ((uint)f2b(fmaf(v[3], A1, g)) << 16);
            __builtin_nontemporal_store(lv, dl + idx);
            __builtin_nontemporal_store(cv, dc + idx);
        }
    }
}

// ---------------------------------------------------------------- launch
extern "C" void kernel_launch(void* const* d_in, const int* in_sizes, int n_in,
                              void* d_out, int out_size, void* d_ws, size_t ws_size,
                              hipStream_t stream) {
    const int* X = (const int*)d_in[0];
    const int* y = (const int*)d_in[1];

    char* ws = (char*)d_ws;
    ushort_t* conv     = (ushort_t*)(ws);              // 1.03 MB
    ushort_t* WT1      = (ushort_t*)(ws + 1048576);    // 512 KB
    ushort_t* WT2      = (ushort_t*)(ws + 1572864);    // 512 KB
    ushort_t* h1       = (ushort_t*)(ws + 2097152);    // 1 MB
    float*    tableRaw = (float*)(ws + 3145728);       // 20 KB

    prep_kernel<<<dim3(1033, 1, 1), 256, 0, stream>>>(
        d_in[2], d_in[3], d_in[4], d_in[5], d_in[6],
        conv, WT1, WT2, tableRaw);
    mlp_layer<<<dim3(16, 32, 1), 256, 0, stream>>>(
        conv + OFF_EMB, WT1, conv + OFF_B1, h1, SS - 1);
    mlp2_kernel<<<dim3(16, 32, 1), 256, 0, stream>>>(
        h1, WT2, conv + OFF_B2, d_in[7], (const uint*)d_in[2], tableRaw);
    scan_kernel<<<dim3(2048, 1, 1), 256, 0, stream>>>(
        X, y, tableRaw, d_in[8], (const uint*)d_in[2], (void*)d_out);
}

// Round 12
// 203.412 us; speedup vs baseline: 1.1081x; 1.1081x over previous
//
#include <hip/hip_runtime.h>

// MLP depends only on X[b] (1000 distinct values) -> params table, gathered
// by the scan. R12: revert R11's mlp2-atomic fusion (regressed); scan split
// back into two pipeline-friendly kernels (R11 profile: fused scan = 62us
// @1.7TB/s — barrier-serialized phases at 5 blocks/CU; split kernels
// pipeline across the grid). scan_a now chains with FULL 64-lane waves.
// Kept lessons: R5 strided stores = 4.85x write amp -> LDS tile + contiguous
// stores; R7 grid.sync ~60us/barrier; R8 per-load dtype branch = latency
// death; NT stores dropped (suspect in low store BW).

typedef unsigned int uint;
typedef unsigned char uchar;
typedef unsigned short ushort_t;
typedef __attribute__((ext_vector_type(8))) short short8;
typedef __attribute__((ext_vector_type(4))) float f32x4;
typedef __attribute__((ext_vector_type(2))) uint uint2v;

#define SS 1000
#define HH 512
#define TT 200
#define BB_ 65536
#define PP 5

#define OFF_EMB   0
#define OFF_B1    512000
#define OFF_B2    512512
#define OFF_WOUT  513024
#define OFF_BOUT  515584
#define CONV_TOT  515589

__device__ __forceinline__ float b2f(ushort_t u) {
    return __uint_as_float(((uint)u) << 16);
}
__device__ __forceinline__ ushort_t f2b(float f) {
    uint u = __float_as_uint(f);
    uint r = u + 0x7FFFu + ((u >> 16) & 1u);   // RNE
    return (ushort_t)(r >> 16);
}
// Per-wave dtype detect (R2-R11: dataset is f32; keep both paths).
__device__ __forceinline__ int detect_bf16(const uint* __restrict__ embed_raw,
                                           int tid) {
    uint w = embed_raw[tid & 63];
    uint e = (w >> 7) & 0xFFu;
    bool pl = (e >= 117u && e <= 130u);
    return __popcll(__ballot(pl)) >= 32 ? 1 : 0;
}
__device__ __forceinline__ ushort_t ld_bf16(const void* src, int idx, int fb) {
    return fb ? ((const ushort_t*)src)[idx] : f2b(((const float*)src)[idx]);
}

// The one true scan step (same fp ops/order in scan_a and scan_b so
// checkpoint-resumed trajectories are bit-exact).
__device__ __forceinline__ float bkt_step(float latent, bool yt,
                                          float oms, float omg, float A1,
                                          float A0, float g, float s,
                                          float oml, float l) {
    float num1    = latent * oms;
    float correct = fmaf(latent, A1, g);
    float lats    = latent * s;
    float num = yt ? num1 : lats;
    float den = yt ? correct : fmaf(latent, A0, omg);
    float kt  = num * __builtin_amdgcn_rcpf(den);
    float nxt = fmaf(kt, oml, l);
    return fminf(fmaxf(nxt, 1e-6f), 1.f - 1e-6f);
}

// ------------------------------------------------------------------- prep
// [0,504): vectorized conv copy. [504,1016): 32x32 transpose tiles W1/W2.
__global__ __launch_bounds__(256) void prep_kernel(
    const void* __restrict__ embed, const void* __restrict__ W1,
    const void* __restrict__ b1,    const void* __restrict__ W2,
    const void* __restrict__ b2,    const void* __restrict__ Wout,
    const void* __restrict__ bout,
    ushort_t* __restrict__ conv, ushort_t* __restrict__ WT1,
    ushort_t* __restrict__ WT2)
{
    int tid = threadIdx.x;
    int fb = detect_bf16((const uint*)embed, tid);
    int bx = blockIdx.x;
    if (bx < 504) {
        int i = (bx * 256 + tid) * 4;
        if (i < CONV_TOT) {
            const void* src; int off;
            if      (i < OFF_B1)   { src = embed; off = i; }
            else if (i < OFF_B2)   { src = b1;    off = i - OFF_B1; }
            else if (i < OFF_WOUT) { src = b2;    off = i - OFF_B2; }
            else if (i < OFF_BOUT) { src = Wout;  off = i - OFF_WOUT; }
            else                   { src = bout;  off = i - OFF_BOUT; }
            if (i + 3 < CONV_TOT) {
                ushort4 o;
                if (fb) {
                    o = *(const ushort4*)((const ushort_t*)src + off);
                } else {
                    float4 v = *(const float4*)((const float*)src + off);
                    o.x = f2b(v.x); o.y = f2b(v.y); o.z = f2b(v.z); o.w = f2b(v.w);
                }
                *(ushort4*)(conv + i) = o;
            } else {
                for (int k = 0; i + k < CONV_TOT; k++)
                    conv[i + k] = ld_bf16(src, off + k, fb);
            }
        }
    } else {
        __shared__ ushort_t t[32][33];
        int bi = bx - 504;
        const void* W = bi < 256 ? W1 : W2;
        ushort_t* WT = bi < 256 ? WT1 : WT2;
        int ti = bi & 255;
        int k0 = (ti & 15) * 32, n0 = (ti >> 4) * 32;
        int tx = tid & 31, ty = tid >> 5;
        #pragma unroll
        for (int i = ty; i < 32; i += 8)
            t[i][tx] = ld_bf16(W, (k0 + i) * HH + n0 + tx, fb);
        __syncthreads();
        #pragma unroll
        for (int i = ty; i < 32; i += 8)
            WT[(n0 + i) * HH + k0 + tx] = t[tx][i];
    }
}

// -------------------------------------------------------------- MLP layer
// Wave computes a 16x16 MFMA tile; grid (16,32)=512 blocks (2/CU).
__global__ __launch_bounds__(256) void mlp_layer(
    const ushort_t* __restrict__ A, const ushort_t* __restrict__ WT,
    const ushort_t* __restrict__ bias, ushort_t* __restrict__ H, int Mclamp)
{
    int tid = threadIdx.x;
    int lane = tid & 63;
    int wave = tid >> 6;
    int m_base = blockIdx.x * 64 + wave * 16;
    int n_base = blockIdx.y * 16;
    int lrow = lane & 15;
    int q = lane >> 4;
    int rowA = m_base + lrow; if (rowA > Mclamp) rowA = Mclamp;

    const short8* Ap = (const short8*)(A + (size_t)rowA * HH) + q;
    const short8* Bp = (const short8*)(WT + (size_t)(n_base + lrow) * HH) + q;

    f32x4 acc = {0.f, 0.f, 0.f, 0.f};
    #pragma unroll 8
    for (int kk = 0; kk < 16; kk++) {
        short8 a = Ap[kk * 4];
        short8 b = Bp[kk * 4];
        acc = __builtin_amdgcn_mfma_f32_16x16x32_bf16(a, b, acc, 0, 0, 0);
    }

    int orow = m_base + q * 4;                 // C/D: col=lane&15, row=q*4+reg
    int n = n_base + lrow;
    float bb = b2f(bias[n]);
    #pragma unroll
    for (int r = 0; r < 4; r++) {
        float v = acc[r] + bb;
        H[(size_t)(orow + r) * HH + n] = f2b(fmaxf(v, 0.f));
    }
}

// ---------------------------------------------------------------- params
__global__ __launch_bounds__(256) void params_kernel(
    const ushort_t* __restrict__ h2, const ushort_t* __restrict__ conv,
    float* __restrict__ table)
{
    int wid = blockIdx.x * 4 + (threadIdx.x >> 6);
    int lane = threadIdx.x & 63;
    if (wid >= SS * PP) return;
    int row = wid / PP, p = wid - row * PP;
    const ushort_t* Wout = conv + OFF_WOUT;
    const ushort_t* bout = conv + OFF_BOUT;
    const short8* hr = (const short8*)(h2 + (size_t)row * HH);
    short8 h = hr[lane];
    float acc = 0.f;
    #pragma unroll
    for (int j = 0; j < 8; j++) {
        int k = lane * 8 + j;
        acc += b2f((ushort_t)h[j]) * b2f(Wout[k * PP + p]);
    }
    #pragma unroll
    for (int m = 32; m; m >>= 1) acc += __shfl_xor(acc, m);
    if (lane == 0) {
        float x = acc + b2f(bout[p]);
        float sg = 1.f / (1.f + expf(-x));
        sg = fminf(fmaxf(sg, 1e-6f), 1.f - 1e-6f);
        table[(size_t)row * 8 + p] = sg;
    }
}

// ---------------------------------------------------------------- scan_a
// 512 blocks x 256, 128 rows/block. y staged coalesced -> LDS nibbles; then
// waves 0-1 chain 128 rows with FULL 64-lane utilization (200 exact steps,
// latent-only), writing 8 checkpoints + 8 masks per row, planar-coalesced.
__global__ __launch_bounds__(256) void scan_a(
    const int* __restrict__ X, const int* __restrict__ y,
    const float* __restrict__ table,
    float* __restrict__ cpA, uint* __restrict__ maskA)
{
    __shared__ uchar ybit[128 * 50];           // 6400 B
    int tid = threadIdx.x;
    int rbase = blockIdx.x * 128;

    for (int idx = tid; idx < 6400; idx += 256) {
        int r = idx / 50, k = idx - r * 50;
        int4 v = *(const int4*)(y + (size_t)(rbase + r) * TT + k * 4);
        ybit[r * 50 + k] = (uchar)((uint)(v.x == 1) | ((uint)(v.y == 1) << 1) |
                                   ((uint)(v.z == 1) << 2) | ((uint)(v.w == 1) << 3));
    }
    __syncthreads();

    if (tid < 128) {
        int rg = rbase + tid;
        int xi = X[rg]; xi = xi < 0 ? 0 : (xi >= SS ? SS - 1 : xi);
        float l      = table[xi * 8 + 0];
        float g      = table[xi * 8 + 2];
        float s      = table[xi * 8 + 3];
        float latent = table[xi * 8 + 4];
        float oms = 1.f - s, omg = 1.f - g, oml = 1.f - l;
        float A1 = 1.f - s - g, A0 = s + g - 1.f;
        const uchar* yb = &ybit[tid * 50];
        float cp[8]; uint mk[8];
        #pragma unroll
        for (int w = 0; w < 8; w++) {
            cp[w] = latent;
            uint m = 0;
            #pragma unroll
            for (int k = 0; k < 7; k++) {      // 7 nibbles = 28 >= 25 bits
                if (k * 4 >= 25) break;
                uint nib = yb[w * 25 / 4 + 0]; // placeholder (unrolled below)
            }
            // 25 steps: nibble-aligned walk over absolute t = w*25 + i
            #pragma unroll
            for (int i = 0; i < 25; i++) {
                int t_ = w * 25 + i;
                uint bit = (ybit[tid * 50 + (t_ >> 2)] >> (t_ & 3)) & 1u;
                m |= bit << i;
                latent = bkt_step(latent, bit, oms, omg, A1, A0, g, s, oml, l);
            }
            mk[w] = m;
        }
        #pragma unroll
        for (int w = 0; w < 8; w++) {
            cpA[(size_t)w * BB_ + rg]   = cp[w];
            maskA[(size_t)w * BB_ + rg] = mk[w];
        }
    }
}

// ---------------------------------------------------------------- scan_b
// 2048 blocks x 256, 32 rows/block, 8 threads/row. Resume from checkpoint,
// 25-step bit-exact re-emission of latents into a 32x200 LDS tile (2-way
// bank alias = free), one barrier, sweep computes corrects = fma(lat,A1,g)
// and streams both outputs as contiguous plain uint4 stores.
__global__ __launch_bounds__(256) void scan_b(
    const int* __restrict__ X, const float* __restrict__ table,
    const float* __restrict__ cpA, const uint* __restrict__ maskA,
    const uint* __restrict__ embed_raw, void* __restrict__ out)
{
    __shared__ __align__(16) float stg[32 * 200];      // 25600 B
    __shared__ float pA1[32], pG[32];
    int tid = threadIdx.x;
    int rbase = blockIdx.x * 32;
    int fb = detect_bf16(embed_raw, tid);

    int r = tid >> 3, j = tid & 7;
    int rg = rbase + r;
    int xi = X[rg]; xi = xi < 0 ? 0 : (xi >= SS ? SS - 1 : xi);
    float l  = table[xi * 8 + 0];
    float p1 = table[xi * 8 + 1];
    float g  = table[xi * 8 + 2];
    float s  = table[xi * 8 + 3];
    float L0 = table[xi * 8 + 4];

    if (j == 0) { pA1[r] = 1.f - s - g; pG[r] = g; }

    if (j < 5) {
        float pv = j == 0 ? l : j == 1 ? p1 : j == 2 ? g : j == 3 ? s : L0;
        size_t po = 2ull * BB_ * TT + (size_t)rg * 5 + j;
        if (fb) ((ushort_t*)out)[po] = f2b(pv);
        else    ((float*)out)[po] = pv;
    }

    float latent = cpA[(size_t)j * BB_ + rg];
    uint  u      = maskA[(size_t)j * BB_ + rg];
    float oms = 1.f - s, omg = 1.f - g, oml = 1.f - l;
    float A1 = 1.f - s - g, A0 = s + g - 1.f;

    int sbase = r * 200 + j * 25;              // 2-way bank alias = free
    #pragma unroll
    for (int i = 0; i < 25; i++) {
        stg[sbase + i] = latent;
        latent = bkt_step(latent, (u >> i) & 1u,
                          oms, omg, A1, A0, g, s, oml, l);
    }
    __syncthreads();

    const f32x4* src = (const f32x4*)stg;
    if (!fb) {
        f32x4* dc = (f32x4*)((float*)out + (size_t)rbase * TT);
        f32x4* dl = (f32x4*)((float*)out + (size_t)BB_ * TT + (size_t)rbase * TT);
        for (int idx = tid; idx < 1600; idx += 256) {
            int rr = idx / 50;
            f32x4 v = src[idx];
            float a1 = pA1[rr], gg = pG[rr];
            f32x4 c;
            c[0] = fmaf(v[0], a1, gg); c[1] = fmaf(v[1], a1, gg);
            c[2] = fmaf(v[2], a1, gg); c[3] = fmaf(v[3], a1, gg);
            dl[idx] = v;
            dc[idx] = c;
        }
    } else {
        uint2v* dc = (uint2v*)((ushort_t*)out + (size_t)rbase * TT);
        uint2v* dl = (uint2v*)((ushort_t*)out + (size_t)BB_ * TT + (size_t)rbase * TT);
        for (int idx = tid; idx < 1600; idx += 256) {
            int rr = idx / 50;
            f32x4 v = src[idx];
            float a1 = pA1[rr], gg = pG[rr];
            uint2v lv, cv;
            lv[0] = (uint)f2b(v[0]) | ((uint)f2b(v[1]) << 16);
            lv[1] = (uint)f2b(v[2]) | ((uint)f2b(v[3]) << 16);
            cv[0] = (uint)f2b(fmaf(v[0], a1, gg)) | ((uint)f2b(fmaf(v[1], a1, gg)) << 16);
            cv[1] = (uint)f2b(fmaf(v[2], a1, gg)) | ((uint)f2b(fmaf(v[3], a1, gg)) << 16);
            dl[idx] = lv;
            dc[idx] = cv;
        }
    }
}

// ---------------------------------------------------------------- launch
extern "C" void kernel_launch(void* const* d_in, const int* in_sizes, int n_in,
                              void* d_out, int out_size, void* d_ws, size_t ws_size,
                              hipStream_t stream) {
    const int* X = (const int*)d_in[0];
    const int* y = (const int*)d_in[1];

    char* ws = (char*)d_ws;
    ushort_t* conv  = (ushort_t*)(ws);                 // ~1.03 MB
    ushort_t* WT1   = (ushort_t*)(ws + 1048576);       // 512 KB
    ushort_t* WT2   = (ushort_t*)(ws + 1572864);       // 512 KB
    ushort_t* h1    = (ushort_t*)(ws + 2097152);       // 1 MB
    ushort_t* h2    = (ushort_t*)(ws + 3145728);       // 1 MB
    float*    table = (float*)(ws + 4194304);          // 32 KB
    float*    cpA   = (float*)(ws + 4227072);          // 2 MB
    uint*     maskA = (uint*)(ws + 6324224);           // 2 MB

    prep_kernel<<<dim3(1016, 1, 1), 256, 0, stream>>>(
        d_in[2], d_in[3], d_in[4], d_in[5], d_in[6], d_in[7], d_in[8],
        conv, WT1, WT2);
    mlp_layer<<<dim3(16, 32, 1), 256, 0, stream>>>(
        conv + OFF_EMB, WT1, conv + OFF_B1, h1, SS - 1);
    mlp_layer<<<dim3(16, 32, 1), 256, 0, stream>>>(
        h1, WT2, conv + OFF_B2, h2, 1023);
    params_kernel<<<dim3(1250, 1, 1), 256, 0, stream>>>(h2, conv, table);
    scan_a<<<dim3(512, 1, 1), 256, 0, stream>>>(X, y, table, cpA, maskA);
    scan_b<<<dim3(2048, 1, 1), 256, 0, stream>>>(
        X, table, cpA, maskA, (const uint*)d_in[2], (void*)d_out);
}